// Round 11
// baseline (199.965 us; speedup 1.0000x reference)
//
#include <hip/hip_runtime.h>

#define NH 12
#define HD 64
#define BB 8
#define SEQ 1024
#define CD 768

typedef __bf16 bf16x8 __attribute__((ext_vector_type(8)));
typedef float f32x4 __attribute__((ext_vector_type(4)));

__device__ __forceinline__ unsigned short f2bf(float f) {
    unsigned int u = __float_as_uint(f);
    u = (u + 0x7fffu + ((u >> 16) & 1u)) >> 16;   // RNE
    return (unsigned short)u;
}

// async global->LDS, 16 bytes per lane (global_load_lds_dwordx4)
__device__ __forceinline__ void gld_lds16(const unsigned short* g, unsigned short* l) {
    __builtin_amdgcn_global_load_lds(
        (const __attribute__((address_space(1))) unsigned int*)g,
        (__attribute__((address_space(3))) unsigned int*)l, 16, 0, 0);
}

// slot->key bit permutation (within a 64-key chunk): PV A-fragment becomes the
// lane's own S^T output registers in order.  Bijective on 0..63.
// slot2key(s) = (s&3) + 4*((s>>3)&3) + 16*((s>>2)&1) + 32*(s>>5)
// inverse (key k = mi*16+quad*4+r): s = r + ((mi&1)<<2) + (quad<<3) + ((mi>>1)<<5)

// ---------------- fused cast fp32 -> bf16 for x / qkv_w / proj_w ------------
#define N4_X 1572864
#define N4_W1 442368
#define N4_W2 147456
__global__ void cast_all(const float* __restrict__ x, const float* __restrict__ w1,
                         const float* __restrict__ w2,
                         unsigned short* __restrict__ ox, unsigned short* __restrict__ ow1,
                         unsigned short* __restrict__ ow2) {
    int i = blockIdx.x * blockDim.x + threadIdx.x;
    const float4* src;
    ushort4* dst;
    if (i < N4_X) {
        src = (const float4*)x + i; dst = (ushort4*)ox + i;
    } else if (i < N4_X + N4_W1) {
        src = (const float4*)w1 + (i - N4_X); dst = (ushort4*)ow1 + (i - N4_X);
    } else if (i < N4_X + N4_W1 + N4_W2) {
        src = (const float4*)w2 + (i - N4_X - N4_W1); dst = (ushort4*)ow2 + (i - N4_X - N4_W1);
    } else return;
    float4 f = *src;
    ushort4 o;
    o.x = f2bf(f.x); o.y = f2bf(f.y); o.z = f2bf(f.z); o.w = f2bf(f.w);
    *dst = o;
}

// ---------------- bf16 MFMA GEMM, BK=32, 128x128, 2-phase double-buffer -----
// [round-8 proven body]  T3-minimum recipe: per iteration -- barrier (lands
// buf[cur]'s async loads + closes reads of buf[cur^1]) -> issue
// global_load_lds for iter+1 into buf[cur^1] -> ds_read+MFMA on buf[cur].
// ONE barrier per K-step; static buffer selection (2x-unrolled, nIt=24 even).
// MODE 0: q(*0.125*log2e)/k natural (BH,SEQ,HD); v written DIRECTLY in
//   chunk-local slotted transpose vt[bh][kc][d][slot] (slot = inverse key
//   permutation) -- per (mi,ni) one ushort4 across 16 d-rows at 128B stride,
//   same stride profile as the proven natural epilogue.  No vtrans kernel.
// MODE 1: fp32 output, row-major M x N
template<int MODE>
__global__ __launch_bounds__(256)
void gemm_bt(const unsigned short* __restrict__ A, const unsigned short* __restrict__ W,
             const float* __restrict__ bias,
             unsigned short* __restrict__ qb, unsigned short* __restrict__ kb,
             unsigned short* __restrict__ vb, float* __restrict__ fout,
             int M, int N, int K) {
    __shared__ __attribute__((aligned(16))) unsigned short As[2][128 * 32];
    __shared__ __attribute__((aligned(16))) unsigned short Bs[2][128 * 32];

    const int t    = threadIdx.x;
    const int bm0  = blockIdx.x * 128;
    const int bn0  = blockIdx.y * 128;
    const int wave = t >> 6;
    const int lane = t & 63;
    const int wm   = (wave >> 1) * 64;
    const int wn   = (wave & 1) * 64;
    const int col  = lane & 15;
    const int quad = lane >> 4;

    const int srow = t >> 2;         // 0..63
    const int scol = (t & 3) * 8;    // 0,8,16,24

    f32x4 acc[4][4];
#pragma unroll
    for (int i = 0; i < 4; i++)
#pragma unroll
        for (int j = 0; j < 4; j++) acc[i][j] = (f32x4){0.f, 0.f, 0.f, 0.f};

    auto stage = [&](int it, unsigned short* Ad, unsigned short* Bd) {
        const int k0 = it << 5;
        gld_lds16(A + (size_t)(bm0 + srow) * K + k0 + scol,      Ad + srow * 32 + scol);
        gld_lds16(A + (size_t)(bm0 + 64 + srow) * K + k0 + scol, Ad + (64 + srow) * 32 + scol);
        gld_lds16(W + (size_t)(bn0 + srow) * K + k0 + scol,      Bd + srow * 32 + scol);
        gld_lds16(W + (size_t)(bn0 + 64 + srow) * K + k0 + scol, Bd + (64 + srow) * 32 + scol);
    };
    auto compute = [&](const unsigned short* Ad, const unsigned short* Bd) {
        bf16x8 af[4], bf[4];
#pragma unroll
        for (int mi = 0; mi < 4; mi++)
            af[mi] = *(const bf16x8*)(Ad + (wm + mi * 16 + col) * 32 + quad * 8);
#pragma unroll
        for (int ni = 0; ni < 4; ni++)
            bf[ni] = *(const bf16x8*)(Bd + (wn + ni * 16 + col) * 32 + quad * 8);
#pragma unroll
        for (int mi = 0; mi < 4; mi++)
#pragma unroll
            for (int ni = 0; ni < 4; ni++)
                acc[mi][ni] = __builtin_amdgcn_mfma_f32_16x16x32_bf16(
                    af[mi], bf[ni], acc[mi][ni], 0, 0, 0);
    };

    const int nIt = K >> 5;          // 24 for both gemms (even)
    stage(0, As[0], Bs[0]);
#pragma unroll 1
    for (int it = 0; it < nIt; it += 2) {
        __syncthreads();             // buf0 loads landed; reads of buf1 closed
        if (it + 1 < nIt) stage(it + 1, As[1], Bs[1]);
        compute(As[0], Bs[0]);
        __syncthreads();             // buf1 loads landed; reads of buf0 closed
        if (it + 2 < nIt) stage(it + 2, As[0], Bs[0]);
        compute(As[1], Bs[1]);
    }

    if (MODE == 1) {
#pragma unroll
        for (int mi = 0; mi < 4; mi++)
#pragma unroll
            for (int ni = 0; ni < 4; ni++) {
                const int n = bn0 + wn + ni * 16 + col;
                const float bv = bias[n];
#pragma unroll
                for (int r = 0; r < 4; r++) {
                    const int m = bm0 + wm + mi * 16 + quad * 4 + r;
                    fout[(size_t)m * N + n] = acc[mi][ni][r] + bv;
                }
            }
        return;
    }

    // MODE 0: all-uniform addressing (no per-element div/mod/branch)
    const int sel = bn0 / 768;              // uniform: 0=q 1=k 2=v
    const int nb  = bn0 - sel * 768;        // uniform head-window base
    const int b   = bm0 >> 10;              // uniform (128 | 1024)
    const int nqb = bm0 & 1023;

    if (sel == 2) {
        // chunk-local slotted V^T: vt[bh][kc][d][slot], 64x64 tiles.
        // Lane's 4 acc values (keys kic = mi*16+quad*4+r of chunk
        // cc0+(wm>>6)) land at 4 consecutive slots s0..s0+3 where
        // s0 = ((mi&1)<<2)+(quad<<3)+((mi>>1)<<5)  [inverse of slot2key].
        const int cc = (nqb >> 6) + (wm >> 6);   // this wave's key chunk
#pragma unroll
        for (int ni = 0; ni < 4; ni++) {
            const int hn = nb + wn + ni * 16;
            const int h  = hn >> 6;
            const int d0 = hn & 63;
            const float bv = bias[bn0 + wn + ni * 16 + col];
            unsigned short* const tile =
                vb + ((size_t)(b * NH + h) * 16 + cc) * 4096
                   + (size_t)(d0 + col) * 64;
#pragma unroll
            for (int mi = 0; mi < 4; mi++) {
                const int s0 = ((mi & 1) << 2) + (quad << 3) + ((mi >> 1) << 5);
                ushort4 o;
                o.x = f2bf(acc[mi][ni][0] + bv);
                o.y = f2bf(acc[mi][ni][1] + bv);
                o.z = f2bf(acc[mi][ni][2] + bv);
                o.w = f2bf(acc[mi][ni][3] + bv);
                *(ushort4*)(tile + s0) = o;
            }
        }
        return;
    }

    unsigned short* const dstbuf = (sel == 0) ? qb : kb;
    // q scale folds softmax's log2e so attn uses exp2:  0.125 * 1.44269504
    const float scale = (sel == 0) ? 0.18033688f : 1.0f;

#pragma unroll
    for (int ni = 0; ni < 4; ni++) {
        const int hn = nb + wn + ni * 16;   // multiple of 16 within 2-head window
        const int h  = hn >> 6;
        const int d0 = hn & 63;
        const float bv = bias[bn0 + wn + ni * 16 + col];
        unsigned short* const rowbase =
            dstbuf + ((size_t)(b * NH + h) * SEQ) * HD + d0 + col;
#pragma unroll
        for (int mi = 0; mi < 4; mi++)
#pragma unroll
            for (int r = 0; r < 4; r++) {
                const int nq = nqb + wm + mi * 16 + quad * 4 + r;
                rowbase[(size_t)nq * HD] = f2bf((acc[mi][ni][r] + bv) * scale);
            }
    }
}

// ---------------- flash attention, bf16 MFMA, 128-query dual-strip ----------
// q,k (BH,SEQ,HD); v chunk-local slotted V^T vt[bh][kc][d][slot] (written by
// gemm0); q pre-scaled by 0.125*log2e.  Round-10 structure: TWO 16-query
// strips per wave share K/V staging, barriers, and fragment ds_reads.
// S^T = mfma(K-frag, Q-frag): lane (col,quad) holds S[q=col][key=16ni+4quad+r];
// with the slot permutation the PV A-fragment is those values packed in
// register order -> P never touches LDS.  K/V double-buffered: ONE barrier
// per chunk; ds_writes (chunk+1) and global loads (chunk+2) overlap compute.
// V^T global reads are now fully coalesced (addr = t*16 within each chunk,
// chunk stride 64*HD -- identical arithmetic to K).  grid (bh=96, qt=8).
__global__ __launch_bounds__(256, 3)
void attn_mfma(const unsigned short* __restrict__ qb,
               const unsigned short* __restrict__ kb,
               const unsigned short* __restrict__ vb,
               unsigned short* __restrict__ ob) {
    __shared__ __attribute__((aligned(16))) unsigned short Ks[2][64 * 72];
    __shared__ __attribute__((aligned(16))) unsigned short VT[2][64 * 72];

    const int t  = threadIdx.x;
    const int bh = blockIdx.x;      // 0..95
    const int qt = blockIdx.y;      // 0..7 (128 queries each)
    const size_t base = (size_t)bh * SEQ * HD;   // same element count for V^T

    const int sr = t >> 2;          // 0..63 staging row (key for K, d for V^T)
    const int sc = (t & 3) * 16;    // staging col base

    const int wave = t >> 6;
    const int lane = t & 63;
    const int col  = lane & 15;
    const int quad = lane >> 4;

    // Q fragments for this wave's two 16-query strips (row=col, k=quad*8+j)
    bf16x8 aq[2][2];
#pragma unroll
    for (int u = 0; u < 2; u++) {
        const int q = qt * 128 + (2 * wave + u) * 16 + col;
        aq[u][0] = *(const bf16x8*)(qb + base + (size_t)q * HD + quad * 8);
        aq[u][1] = *(const bf16x8*)(qb + base + (size_t)q * HD + 32 + quad * 8);
    }

    float l_r[2] = {0.f, 0.f};      // per-lane row-sum partials, query = col
    f32x4 accO[2][4];
#pragma unroll
    for (int u = 0; u < 2; u++)
#pragma unroll
        for (int di = 0; di < 4; di++) accO[u][di] = (f32x4){0.f, 0.f, 0.f, 0.f};

    const unsigned short* kp = kb + base + (size_t)sr * HD + sc;   // K[key][d]
    const unsigned short* vp = vb + base + (size_t)sr * 64 + sc;   // VT[kc][d][slot]
    const int so = sr * 72 + sc;

    // prologue: chunk 0 -> regs -> buf0; then prefetch chunk 1 regs
    uint4 kr0 = *(const uint4*)kp,  kr1 = *(const uint4*)(kp + 8);
    uint4 vr0 = *(const uint4*)vp,  vr1 = *(const uint4*)(vp + 8);
    *(uint4*)(Ks[0] + so)     = kr0;
    *(uint4*)(Ks[0] + so + 8) = kr1;
    *(uint4*)(VT[0] + so)     = vr0;
    *(uint4*)(VT[0] + so + 8) = vr1;
    kr0 = *(const uint4*)(kp + 64 * HD);  kr1 = *(const uint4*)(kp + 64 * HD + 8);
    vr0 = *(const uint4*)(vp + 64 * HD);  vr1 = *(const uint4*)(vp + 64 * HD + 8);

    auto chunk = [&](int kc, const unsigned short* Kc, const unsigned short* Vc,
                     unsigned short* Kn, unsigned short* Vn) {
        __syncthreads();   // buf[kc] writes visible; all waves done with buf[kc-1]
        if (kc < 15) {     // stage chunk kc+1 (regs already hold it)
            *(uint4*)(Kn + so)     = kr0;
            *(uint4*)(Kn + so + 8) = kr1;
            *(uint4*)(Vn + so)     = vr0;
            *(uint4*)(Vn + so + 8) = vr1;
        }
        if (kc < 14) {     // prefetch chunk kc+2 into regs
            const unsigned short* kn = kp + (size_t)(kc + 2) * 64 * HD;
            const unsigned short* vn = vp + (size_t)(kc + 2) * 64 * HD;
            kr0 = *(const uint4*)kn; kr1 = *(const uint4*)(kn + 8);
            vr0 = *(const uint4*)vn; vr1 = *(const uint4*)(vn + 8);
        }

        // S^T for both strips, sharing K-fragment reads:
        // accT[u][ni][r] = S[query=col (strip u)][key=ni*16+quad*4+r]
        f32x4 accT[2][4];
        __builtin_amdgcn_s_setprio(1);
#pragma unroll
        for (int ni = 0; ni < 4; ni++) {
            bf16x8 bk0 = *(const bf16x8*)(Kc + (ni * 16 + col) * 72 + quad * 8);
            bf16x8 bk1 = *(const bf16x8*)(Kc + (ni * 16 + col) * 72 + 32 + quad * 8);
#pragma unroll
            for (int u = 0; u < 2; u++) {
                f32x4 z = (f32x4){0.f, 0.f, 0.f, 0.f};
                z = __builtin_amdgcn_mfma_f32_16x16x32_bf16(bk0, aq[u][0], z, 0, 0, 0);
                z = __builtin_amdgcn_mfma_f32_16x16x32_bf16(bk1, aq[u][1], z, 0, 0, 0);
                accT[u][ni] = z;
            }
        }
        __builtin_amdgcn_s_setprio(0);

        // exp2 (log2e folded into q) -> bf16 pack IN REGISTER ORDER: under
        // VT's slot permutation this IS the PV A-fragment.
        union { __bf16 b[16]; bf16x8 v[2]; } apu[2];
#pragma unroll
        for (int u = 0; u < 2; u++)
#pragma unroll
            for (int ni = 0; ni < 4; ni++) {
                float p0 = __builtin_exp2f(accT[u][ni][0]);
                float p1 = __builtin_exp2f(accT[u][ni][1]);
                float p2 = __builtin_exp2f(accT[u][ni][2]);
                float p3 = __builtin_exp2f(accT[u][ni][3]);
                l_r[u] += (p0 + p1) + (p2 + p3);
                apu[u].b[ni * 4 + 0] = (__bf16)p0;
                apu[u].b[ni * 4 + 1] = (__bf16)p1;
                apu[u].b[ni * 4 + 2] = (__bf16)p2;
                apu[u].b[ni * 4 + 3] = (__bf16)p3;
            }

        // PV for both strips, sharing V-fragment reads (B k-index = slot)
        __builtin_amdgcn_s_setprio(1);
#pragma unroll
        for (int di = 0; di < 4; di++) {
            bf16x8 bv0 = *(const bf16x8*)(Vc + (di * 16 + col) * 72 + quad * 8);
            bf16x8 bv1 = *(const bf16x8*)(Vc + (di * 16 + col) * 72 + 32 + quad * 8);
#pragma unroll
            for (int u = 0; u < 2; u++) {
                accO[u][di] = __builtin_amdgcn_mfma_f32_16x16x32_bf16(apu[u].v[0], bv0, accO[u][di], 0, 0, 0);
                accO[u][di] = __builtin_amdgcn_mfma_f32_16x16x32_bf16(apu[u].v[1], bv1, accO[u][di], 0, 0, 0);
            }
        }
        __builtin_amdgcn_s_setprio(0);
    };

    // static buffer pointers per call (no runtime LDS base selection)
#pragma unroll 1
    for (int kc2 = 0; kc2 < 16; kc2 += 2) {
        chunk(kc2,     Ks[0], VT[0], Ks[1], VT[1]);
        chunk(kc2 + 1, Ks[1], VT[1], Ks[0], VT[0]);
    }

    // epilogue: full row-sums live per-lane at query=col; reduce across quads
    // (xor 16/32), then lane-transpose via __shfl to query=quad*4+r.
    const int b = bh / NH, h = bh - b * NH;
#pragma unroll
    for (int u = 0; u < 2; u++) {
        float s = l_r[u];
        s += __shfl_xor(s, 16);
        s += __shfl_xor(s, 32);
#pragma unroll
        for (int r = 0; r < 4; r++) {
            const float inv = 1.f / __shfl(s, quad * 4 + r);
            const int q = qt * 128 + (2 * wave + u) * 16 + quad * 4 + r;
            const size_t rowbase = ((size_t)b * SEQ + q) * CD + h * 64;
#pragma unroll
            for (int di = 0; di < 4; di++)
                ob[rowbase + di * 16 + col] = f2bf(accO[u][di][r] * inv);
        }
    }
}

// ---------------- host-side launch ----------------
extern "C" void kernel_launch(void* const* d_in, const int* in_sizes, int n_in,
                              void* d_out, int out_size, void* d_ws, size_t ws_size,
                              hipStream_t stream) {
    const float* x      = (const float*)d_in[0];   // 8192*768
    const float* qkv_w  = (const float*)d_in[1];   // 2304*768
    const float* qkv_b  = (const float*)d_in[2];   // 2304
    const float* proj_w = (const float*)d_in[3];   // 768*768
    const float* proj_b = (const float*)d_in[4];   // 768
    float* out = (float*)d_out;

    char* ws = (char*)d_ws;
    unsigned short* x_bf     = (unsigned short*)ws;                  // 12.58 MB
    unsigned short* qkvw_bf  = (unsigned short*)(ws + 12582912);     // 3.54 MB
    unsigned short* projw_bf = (unsigned short*)(ws + 12582912 + 3538944);   // 1.18 MB
    unsigned short* q_bf     = (unsigned short*)(ws + 12582912 + 3538944 + 1179648);
    unsigned short* k_bf     = q_bf + 6291456;
    unsigned short* v_bf     = k_bf + 6291456;     // chunk-local slotted V^T
    // buffer reuse across the dependency chain:
    unsigned short* attn_bf  = x_bf;               // x consumed by gemm0

    cast_all<<<8448, 256, 0, stream>>>(x, qkv_w, proj_w, x_bf, qkvw_bf, projw_bf);

    gemm_bt<0><<<dim3(64, 18), 256, 0, stream>>>(x_bf, qkvw_bf, qkv_b,
                                                 q_bf, k_bf, v_bf, nullptr,
                                                 8192, 2304, 768);

    attn_mfma<<<dim3(96, 8), 256, 0, stream>>>(q_bf, k_bf, v_bf, attn_bf);

    gemm_bt<1><<<dim3(64, 6), 256, 0, stream>>>(attn_bf, projw_bf, proj_b,
                                                nullptr, nullptr, nullptr, out,
                                                8192, 768, 768);
}

// Round 12
// 195.256 us; speedup vs baseline: 1.0241x; 1.0241x over previous
//
#include <hip/hip_runtime.h>

#define NH 12
#define HD 64
#define BB 8
#define SEQ 1024
#define CD 768

typedef __bf16 bf16x8 __attribute__((ext_vector_type(8)));
typedef float f32x4 __attribute__((ext_vector_type(4)));

__device__ __forceinline__ unsigned short f2bf(float f) {
    unsigned int u = __float_as_uint(f);
    u = (u + 0x7fffu + ((u >> 16) & 1u)) >> 16;   // RNE
    return (unsigned short)u;
}

// async global->LDS, 16 bytes per lane (global_load_lds_dwordx4)
__device__ __forceinline__ void gld_lds16(const unsigned short* g, unsigned short* l) {
    __builtin_amdgcn_global_load_lds(
        (const __attribute__((address_space(1))) unsigned int*)g,
        (__attribute__((address_space(3))) unsigned int*)l, 16, 0, 0);
}

// slot->key bit permutation: PV A-fragment becomes the lane's own S^T output
// registers in order (no LDS / no cross-lane for P).  Bijective on 0..63.
__device__ __forceinline__ int slot2key(int s) {
    return (s & 3) + 4 * ((s >> 3) & 3) + 16 * ((s >> 2) & 1) + 32 * (s >> 5);
}

// ---------------- fused cast fp32 -> bf16 for x / qkv_w / proj_w ------------
#define N4_X 1572864
#define N4_W1 442368
#define N4_W2 147456
__global__ void cast_all(const float* __restrict__ x, const float* __restrict__ w1,
                         const float* __restrict__ w2,
                         unsigned short* __restrict__ ox, unsigned short* __restrict__ ow1,
                         unsigned short* __restrict__ ow2) {
    int i = blockIdx.x * blockDim.x + threadIdx.x;
    const float4* src;
    ushort4* dst;
    if (i < N4_X) {
        src = (const float4*)x + i; dst = (ushort4*)ox + i;
    } else if (i < N4_X + N4_W1) {
        src = (const float4*)w1 + (i - N4_X); dst = (ushort4*)ow1 + (i - N4_X);
    } else if (i < N4_X + N4_W1 + N4_W2) {
        src = (const float4*)w2 + (i - N4_X - N4_W1); dst = (ushort4*)ow2 + (i - N4_X - N4_W1);
    } else return;
    float4 f = *src;
    ushort4 o;
    o.x = f2bf(f.x); o.y = f2bf(f.y); o.z = f2bf(f.z); o.w = f2bf(f.w);
    *dst = o;
}

// ---------------- bf16 MFMA GEMM, BK=32, 128x128, 3-buffer counted-vmcnt ----
// T4 applied to the round-8 loop: raw s_barrier + s_waitcnt vmcnt(8) (never 0
// in the main loop) with a 3-buffer rotation -> every tile's 8
// global_load_lds get TWO compute phases to land instead of being drained at
// each __syncthreads.  Ledger: steady state 16 loads in flight (tiles t,t+1);
// vmcnt(8) at tile t waits only the oldest 8 (tile t's).  WAR on
// buf[(t+2)%3] is closed by the barrier (its readers ran at tile t-1).
// Tail drains 8 -> 8 -> 0.  Requires nIt % 3 == 0 (nIt = 24 here).
// MODE 0: scatter into q(*0.125*log2e)/k/v bf16, all (BH,SEQ,HD).
// MODE 1: fp32 output, row-major M x N
template<int MODE>
__global__ __launch_bounds__(256)
void gemm_bt(const unsigned short* __restrict__ A, const unsigned short* __restrict__ W,
             const float* __restrict__ bias,
             unsigned short* __restrict__ qb, unsigned short* __restrict__ kb,
             unsigned short* __restrict__ vb, float* __restrict__ fout,
             int M, int N, int K) {
    __shared__ __attribute__((aligned(16))) unsigned short As[3][128 * 32];
    __shared__ __attribute__((aligned(16))) unsigned short Bs[3][128 * 32];

    const int t    = threadIdx.x;
    const int bm0  = blockIdx.x * 128;
    const int bn0  = blockIdx.y * 128;
    const int wave = t >> 6;
    const int lane = t & 63;
    const int wm   = (wave >> 1) * 64;
    const int wn   = (wave & 1) * 64;
    const int col  = lane & 15;
    const int quad = lane >> 4;

    const int srow = t >> 2;         // 0..63
    const int scol = (t & 3) * 8;    // 0,8,16,24

    f32x4 acc[4][4];
#pragma unroll
    for (int i = 0; i < 4; i++)
#pragma unroll
        for (int j = 0; j < 4; j++) acc[i][j] = (f32x4){0.f, 0.f, 0.f, 0.f};

    auto stage = [&](int it, unsigned short* Ad, unsigned short* Bd) {
        const int k0 = it << 5;
        gld_lds16(A + (size_t)(bm0 + srow) * K + k0 + scol,      Ad + srow * 32 + scol);
        gld_lds16(A + (size_t)(bm0 + 64 + srow) * K + k0 + scol, Ad + (64 + srow) * 32 + scol);
        gld_lds16(W + (size_t)(bn0 + srow) * K + k0 + scol,      Bd + srow * 32 + scol);
        gld_lds16(W + (size_t)(bn0 + 64 + srow) * K + k0 + scol, Bd + (64 + srow) * 32 + scol);
    };
    auto compute = [&](const unsigned short* Ad, const unsigned short* Bd) {
        bf16x8 af[4], bf[4];
#pragma unroll
        for (int mi = 0; mi < 4; mi++)
            af[mi] = *(const bf16x8*)(Ad + (wm + mi * 16 + col) * 32 + quad * 8);
#pragma unroll
        for (int ni = 0; ni < 4; ni++)
            bf[ni] = *(const bf16x8*)(Bd + (wn + ni * 16 + col) * 32 + quad * 8);
#pragma unroll
        for (int mi = 0; mi < 4; mi++)
#pragma unroll
            for (int ni = 0; ni < 4; ni++)
                acc[mi][ni] = __builtin_amdgcn_mfma_f32_16x16x32_bf16(
                    af[mi], bf[ni], acc[mi][ni], 0, 0, 0);
    };
    // own 8 oldest loads landed -> barrier -> whole tile visible to all waves
    auto wait8_bar = [&]() {
        asm volatile("s_waitcnt vmcnt(8)" ::: "memory");
        __builtin_amdgcn_s_barrier();
        __builtin_amdgcn_sched_barrier(0);
    };

    const int nIt = K >> 5;          // 24 for both gemms (divisible by 3)
    stage(0, As[0], Bs[0]);
    stage(1, As[1], Bs[1]);
#pragma unroll 1
    for (int it = 0; it < nIt - 3; it += 3) {
        wait8_bar();                     // tile it landed; t+1 in flight
        stage(it + 2, As[2], Bs[2]);
        compute(As[0], Bs[0]);
        wait8_bar();                     // tile it+1 landed
        stage(it + 3, As[0], Bs[0]);
        compute(As[1], Bs[1]);
        wait8_bar();                     // tile it+2 landed
        stage(it + 4, As[1], Bs[1]);
        compute(As[2], Bs[2]);
    }
    // tail: tiles nIt-3 (b0), nIt-2 (b1), nIt-1 (b2)
    wait8_bar();
    stage(nIt - 1, As[2], Bs[2]);
    compute(As[0], Bs[0]);
    wait8_bar();
    compute(As[1], Bs[1]);
    asm volatile("s_waitcnt vmcnt(0)" ::: "memory");
    __builtin_amdgcn_s_barrier();
    __builtin_amdgcn_sched_barrier(0);
    compute(As[2], Bs[2]);

    if (MODE == 1) {
#pragma unroll
        for (int mi = 0; mi < 4; mi++)
#pragma unroll
            for (int ni = 0; ni < 4; ni++) {
                const int n = bn0 + wn + ni * 16 + col;
                const float bv = bias[n];
#pragma unroll
                for (int r = 0; r < 4; r++) {
                    const int m = bm0 + wm + mi * 16 + quad * 4 + r;
                    fout[(size_t)m * N + n] = acc[mi][ni][r] + bv;
                }
            }
        return;
    }

    // MODE 0: all-uniform addressing (no per-element div/mod/branch)
    const int sel = bn0 / 768;              // uniform: 0=q 1=k 2=v
    const int nb  = bn0 - sel * 768;        // uniform head-window base
    const int b   = bm0 >> 10;              // uniform (128 | 1024)
    const int nqb = bm0 & 1023;
    unsigned short* const dstbuf = (sel == 0) ? qb : (sel == 1) ? kb : vb;
    // q scale folds softmax's log2e so attn uses exp2:  0.125 * 1.44269504
    const float scale = (sel == 0) ? 0.18033688f : 1.0f;

#pragma unroll
    for (int ni = 0; ni < 4; ni++) {
        const int hn = nb + wn + ni * 16;   // multiple of 16 within 2-head window
        const int h  = hn >> 6;
        const int d0 = hn & 63;
        const float bv = bias[bn0 + wn + ni * 16 + col];
        unsigned short* const rowbase =
            dstbuf + ((size_t)(b * NH + h) * SEQ) * HD + d0 + col;
#pragma unroll
        for (int mi = 0; mi < 4; mi++)
#pragma unroll
            for (int r = 0; r < 4; r++) {
                const int nq = nqb + wm + mi * 16 + quad * 4 + r;
                rowbase[(size_t)nq * HD] = f2bf((acc[mi][ni][r] + bv) * scale);
            }
    }
}

// ---------------- V transpose: (BH,SEQ,HD) -> (BH,HD,SEQ), slot-permuted ----
// Within each 64-key block, column s holds key slot2key(s) so attention's PV
// A-fragment is a pure register relabel of the S^T output (no P LDS at all).
__global__ __launch_bounds__(256)
void vtrans(const unsigned short* __restrict__ v, unsigned short* __restrict__ vt) {
    __shared__ __attribute__((aligned(16))) unsigned short T[64 * 72];
    const int bh = blockIdx.x;       // 0..95
    const int kt = blockIdx.y;       // 0..15
    const int t  = threadIdx.x;
    const int r  = t >> 2;           // 0..63
    const int c  = (t & 3) * 16;     // 0,16,32,48

    const unsigned short* src = v + ((size_t)bh * SEQ + kt * 64 + r) * HD + c;
    *(uint4*)(T + r * 72 + c)     = *(const uint4*)src;
    *(uint4*)(T + r * 72 + c + 8) = *(const uint4*)(src + 8);
    __syncthreads();

    // lane writes d-row r, slot columns c..c+15 (permuted gather from LDS)
    union { unsigned short us[16]; uint4 u4[2]; } o;
#pragma unroll
    for (int j = 0; j < 16; j++) o.us[j] = T[slot2key(c + j) * 72 + r];
    unsigned short* dst = vt + ((size_t)bh * HD + r) * SEQ + kt * 64 + c;
    *(uint4*)dst       = o.u4[0];
    *(uint4*)(dst + 8) = o.u4[1];
}

// ---------------- flash attention, bf16 MFMA, 128-query dual-strip ----------
// [round-10 proven body, unchanged]
// q,k (BH,SEQ,HD); v TRANSPOSED+slot-permuted (BH,HD,SEQ); q pre-scaled by
// 0.125*log2e.  TWO 16-query strips per wave share K/V staging, barriers, and
// fragment ds_reads.  S^T = mfma(K-frag, Q-frag); with VT's slot2key column
// order the PV A-fragment is the lane's own registers -> P never touches LDS.
// K/V double-buffered: ONE barrier per chunk; ds_writes (chunk+1) and global
// loads (chunk+2) overlap compute.  grid (bh=96, qt=8): 3 blocks/CU.
__global__ __launch_bounds__(256, 3)
void attn_mfma(const unsigned short* __restrict__ qb,
               const unsigned short* __restrict__ kb,
               const unsigned short* __restrict__ vb,
               unsigned short* __restrict__ ob) {
    __shared__ __attribute__((aligned(16))) unsigned short Ks[2][64 * 72];
    __shared__ __attribute__((aligned(16))) unsigned short VT[2][64 * 72];

    const int t  = threadIdx.x;
    const int bh = blockIdx.x;      // 0..95
    const int qt = blockIdx.y;      // 0..7 (128 queries each)
    const size_t base = (size_t)bh * SEQ * HD;   // same element count for V^T

    const int sr = t >> 2;          // 0..63 staging row (key for K, d for V^T)
    const int sc = (t & 3) * 16;    // staging col base

    const int wave = t >> 6;
    const int lane = t & 63;
    const int col  = lane & 15;
    const int quad = lane >> 4;

    // Q fragments for this wave's two 16-query strips (row=col, k=quad*8+j)
    bf16x8 aq[2][2];
#pragma unroll
    for (int u = 0; u < 2; u++) {
        const int q = qt * 128 + (2 * wave + u) * 16 + col;
        aq[u][0] = *(const bf16x8*)(qb + base + (size_t)q * HD + quad * 8);
        aq[u][1] = *(const bf16x8*)(qb + base + (size_t)q * HD + 32 + quad * 8);
    }

    float l_r[2] = {0.f, 0.f};      // per-lane row-sum partials, query = col
    f32x4 accO[2][4];
#pragma unroll
    for (int u = 0; u < 2; u++)
#pragma unroll
        for (int di = 0; di < 4; di++) accO[u][di] = (f32x4){0.f, 0.f, 0.f, 0.f};

    const unsigned short* kp = kb + base + (size_t)sr * HD + sc;          // K[key][d]
    const unsigned short* vp = vb + base + (size_t)sr * SEQ + sc;         // VT[d][slot]
    const int so = sr * 72 + sc;

    // prologue: chunk 0 -> regs -> buf0; then prefetch chunk 1 regs
    uint4 kr0 = *(const uint4*)kp,  kr1 = *(const uint4*)(kp + 8);
    uint4 vr0 = *(const uint4*)vp,  vr1 = *(const uint4*)(vp + 8);
    *(uint4*)(Ks[0] + so)     = kr0;
    *(uint4*)(Ks[0] + so + 8) = kr1;
    *(uint4*)(VT[0] + so)     = vr0;
    *(uint4*)(VT[0] + so + 8) = vr1;
    kr0 = *(const uint4*)(kp + 64 * HD);  kr1 = *(const uint4*)(kp + 64 * HD + 8);
    vr0 = *(const uint4*)(vp + 64);       vr1 = *(const uint4*)(vp + 64 + 8);

    auto chunk = [&](int kc, const unsigned short* Kc, const unsigned short* Vc,
                     unsigned short* Kn, unsigned short* Vn) {
        __syncthreads();   // buf[kc] writes visible; all waves done with buf[kc-1]
        if (kc < 15) {     // stage chunk kc+1 (regs already hold it)
            *(uint4*)(Kn + so)     = kr0;
            *(uint4*)(Kn + so + 8) = kr1;
            *(uint4*)(Vn + so)     = vr0;
            *(uint4*)(Vn + so + 8) = vr1;
        }
        if (kc < 14) {     // prefetch chunk kc+2 into regs
            const unsigned short* kn = kp + (size_t)(kc + 2) * 64 * HD;
            const unsigned short* vn = vp + (size_t)(kc + 2) * 64;
            kr0 = *(const uint4*)kn; kr1 = *(const uint4*)(kn + 8);
            vr0 = *(const uint4*)vn; vr1 = *(const uint4*)(vn + 8);
        }

        // S^T for both strips, sharing K-fragment reads:
        // accT[u][ni][r] = S[query=col (strip u)][key=ni*16+quad*4+r]
        f32x4 accT[2][4];
        __builtin_amdgcn_s_setprio(1);
#pragma unroll
        for (int ni = 0; ni < 4; ni++) {
            bf16x8 bk0 = *(const bf16x8*)(Kc + (ni * 16 + col) * 72 + quad * 8);
            bf16x8 bk1 = *(const bf16x8*)(Kc + (ni * 16 + col) * 72 + 32 + quad * 8);
#pragma unroll
            for (int u = 0; u < 2; u++) {
                f32x4 z = (f32x4){0.f, 0.f, 0.f, 0.f};
                z = __builtin_amdgcn_mfma_f32_16x16x32_bf16(bk0, aq[u][0], z, 0, 0, 0);
                z = __builtin_amdgcn_mfma_f32_16x16x32_bf16(bk1, aq[u][1], z, 0, 0, 0);
                accT[u][ni] = z;
            }
        }
        __builtin_amdgcn_s_setprio(0);

        // exp2 (log2e folded into q) -> bf16 pack IN REGISTER ORDER: under
        // VT's slot2key column permutation this IS the PV A-fragment.
        union { __bf16 b[16]; bf16x8 v[2]; } apu[2];
#pragma unroll
        for (int u = 0; u < 2; u++)
#pragma unroll
            for (int ni = 0; ni < 4; ni++) {
                float p0 = __builtin_exp2f(accT[u][ni][0]);
                float p1 = __builtin_exp2f(accT[u][ni][1]);
                float p2 = __builtin_exp2f(accT[u][ni][2]);
                float p3 = __builtin_exp2f(accT[u][ni][3]);
                l_r[u] += (p0 + p1) + (p2 + p3);
                apu[u].b[ni * 4 + 0] = (__bf16)p0;
                apu[u].b[ni * 4 + 1] = (__bf16)p1;
                apu[u].b[ni * 4 + 2] = (__bf16)p2;
                apu[u].b[ni * 4 + 3] = (__bf16)p3;
            }

        // PV for both strips, sharing V-fragment reads (B k-index = slot)
        __builtin_amdgcn_s_setprio(1);
#pragma unroll
        for (int di = 0; di < 4; di++) {
            bf16x8 bv0 = *(const bf16x8*)(Vc + (di * 16 + col) * 72 + quad * 8);
            bf16x8 bv1 = *(const bf16x8*)(Vc + (di * 16 + col) * 72 + 32 + quad * 8);
#pragma unroll
            for (int u = 0; u < 2; u++) {
                accO[u][di] = __builtin_amdgcn_mfma_f32_16x16x32_bf16(apu[u].v[0], bv0, accO[u][di], 0, 0, 0);
                accO[u][di] = __builtin_amdgcn_mfma_f32_16x16x32_bf16(apu[u].v[1], bv1, accO[u][di], 0, 0, 0);
            }
        }
        __builtin_amdgcn_s_setprio(0);
    };

    // static buffer pointers per call (no runtime LDS base selection)
#pragma unroll 1
    for (int kc2 = 0; kc2 < 16; kc2 += 2) {
        chunk(kc2,     Ks[0], VT[0], Ks[1], VT[1]);
        chunk(kc2 + 1, Ks[1], VT[1], Ks[0], VT[0]);
    }

    // epilogue: full row-sums live per-lane at query=col; reduce across quads
    // (xor 16/32), then lane-transpose via __shfl to query=quad*4+r.
    const int b = bh / NH, h = bh - b * NH;
#pragma unroll
    for (int u = 0; u < 2; u++) {
        float s = l_r[u];
        s += __shfl_xor(s, 16);
        s += __shfl_xor(s, 32);
#pragma unroll
        for (int r = 0; r < 4; r++) {
            const float inv = 1.f / __shfl(s, quad * 4 + r);
            const int q = qt * 128 + (2 * wave + u) * 16 + quad * 4 + r;
            const size_t rowbase = ((size_t)b * SEQ + q) * CD + h * 64;
#pragma unroll
            for (int di = 0; di < 4; di++)
                ob[rowbase + di * 16 + col] = f2bf(accO[u][di][r] * inv);
        }
    }
}

// ---------------- host-side launch ----------------
extern "C" void kernel_launch(void* const* d_in, const int* in_sizes, int n_in,
                              void* d_out, int out_size, void* d_ws, size_t ws_size,
                              hipStream_t stream) {
    const float* x      = (const float*)d_in[0];   // 8192*768
    const float* qkv_w  = (const float*)d_in[1];   // 2304*768
    const float* qkv_b  = (const float*)d_in[2];   // 2304
    const float* proj_w = (const float*)d_in[3];   // 768*768
    const float* proj_b = (const float*)d_in[4];   // 768
    float* out = (float*)d_out;

    char* ws = (char*)d_ws;
    unsigned short* x_bf     = (unsigned short*)ws;                  // 12.58 MB
    unsigned short* qkvw_bf  = (unsigned short*)(ws + 12582912);     // 3.54 MB
    unsigned short* projw_bf = (unsigned short*)(ws + 12582912 + 3538944);   // 1.18 MB
    unsigned short* q_bf     = (unsigned short*)(ws + 12582912 + 3538944 + 1179648);
    unsigned short* k_bf     = q_bf + 6291456;
    unsigned short* v_bf     = k_bf + 6291456;     // natural (BH,SEQ,HD)
    // buffer reuse across the dependency chain:
    unsigned short* vt_bf    = x_bf;               // x consumed by gemm0
    unsigned short* attn_bf  = v_bf;               // v consumed by vtrans

    cast_all<<<8448, 256, 0, stream>>>(x, qkv_w, proj_w, x_bf, qkvw_bf, projw_bf);

    gemm_bt<0><<<dim3(64, 18), 256, 0, stream>>>(x_bf, qkvw_bf, qkv_b,
                                                 q_bf, k_bf, v_bf, nullptr,
                                                 8192, 2304, 768);

    vtrans<<<dim3(96, 16), 256, 0, stream>>>(v_bf, vt_bf);

    attn_mfma<<<dim3(96, 8), 256, 0, stream>>>(q_bf, k_bf, vt_bf, attn_bf);

    gemm_bt<1><<<dim3(64, 6), 256, 0, stream>>>(attn_bf, projw_bf, proj_b,
                                                nullptr, nullptr, nullptr, out,
                                                8192, 768, 768);
}